// Round 1
// baseline (774.287 us; speedup 1.0000x reference)
//
#include <hip/hip_runtime.h>
#include <hip/hip_bf16.h>

#define DHID 128
#define NH 12
#define KDIM 1536   // NH * DHID

typedef __attribute__((ext_vector_type(8))) short short8;
typedef __attribute__((ext_vector_type(4))) float f32x4;

static __device__ __forceinline__ unsigned short f2bf(float f) {
  __hip_bfloat16 h = __float2bfloat16(f);
  return __builtin_bit_cast(unsigned short, h);
}

// ---------------- sort (counting sort of edges by dst) ----------------

__global__ void hist_k(const int* __restrict__ dstp, int* __restrict__ cnt, int e0, int et) {
  int e = blockIdx.x * blockDim.x + threadIdx.x;
  if (e >= et) return;
  int d = (e < e0) ? dstp[e] : (e - e0);   // self-loop edges appended at the end
  atomicAdd(&cnt[d], 1);
}

__global__ void scan_k(const int* __restrict__ cnt, int* __restrict__ row_start,
                       int* __restrict__ cursor, int n, int total) {
  __shared__ int part[1024];
  int t = threadIdx.x;
  const int CH = (n + 1023) >> 10;
  int base = t * CH;
  int s = 0;
  for (int j = 0; j < CH; ++j) { int i = base + j; if (i < n) s += cnt[i]; }
  part[t] = s;
  __syncthreads();
  for (int off = 1; off < 1024; off <<= 1) {
    int v = (t >= off) ? part[t - off] : 0;
    __syncthreads();
    part[t] += v;
    __syncthreads();
  }
  int run = (t == 0) ? 0 : part[t - 1];
  for (int j = 0; j < CH; ++j) {
    int i = base + j;
    if (i < n) { row_start[i] = run; cursor[i] = run; run += cnt[i]; }
  }
  if (t == 0) row_start[n] = total;
}

__global__ void scatter_k(const int* __restrict__ dstp, int* __restrict__ cursor,
                          int* __restrict__ sorted, int e0, int et) {
  int e = blockIdx.x * blockDim.x + threadIdx.x;
  if (e >= et) return;
  int d = (e < e0) ? dstp[e] : (e - e0);
  int pos = atomicAdd(&cursor[d], 1);
  sorted[pos] = e;
}

// ---------------- per-node u = x . Wu[h] ----------------

__global__ void u_k(const float* __restrict__ x, const float* __restrict__ Wu,
                    float* __restrict__ u, int n) {
  int wid = (blockIdx.x * blockDim.x + threadIdx.x) >> 6;
  if (wid >= n) return;
  int lane = threadIdx.x & 63;
  float2 xv = *(const float2*)(x + (long)wid * DHID + 2 * lane);
  #pragma unroll
  for (int h = 0; h < NH; ++h) {
    float2 wv = *(const float2*)(Wu + h * DHID + 2 * lane);
    float p = xv.x * wv.x + xv.y * wv.y;
    p += __shfl_xor(p, 1);  p += __shfl_xor(p, 2);  p += __shfl_xor(p, 4);
    p += __shfl_xor(p, 8);  p += __shfl_xor(p, 16); p += __shfl_xor(p, 32);
    if (lane == 0) u[wid * NH + h] = p;
  }
}

// ---------------- edge aggregation: A[n,h,:] = sum_e att[e,h] * x[src_e] ----------------

__global__ void edge_k(const float* __restrict__ x, const float* __restrict__ u,
                       const float* __restrict__ cvec, const int* __restrict__ srcp,
                       const int* __restrict__ row_start, const int* __restrict__ sorted,
                       unsigned short* __restrict__ A, int n, int e0) {
  int wid = (blockIdx.x * blockDim.x + threadIdx.x) >> 6;
  if (wid >= n) return;
  int lane = threadIdx.x & 63;
  float uic[NH];
  {
    const float4* up = (const float4*)(u + (long)wid * NH);
    const float4* cp = (const float4*)cvec;
    float4 a0 = up[0], a1 = up[1], a2 = up[2];
    float4 c0 = cp[0], c1 = cp[1], c2 = cp[2];
    uic[0]=a0.x+c0.x; uic[1]=a0.y+c0.y; uic[2]=a0.z+c0.z; uic[3]=a0.w+c0.w;
    uic[4]=a1.x+c1.x; uic[5]=a1.y+c1.y; uic[6]=a1.z+c1.z; uic[7]=a1.w+c1.w;
    uic[8]=a2.x+c2.x; uic[9]=a2.y+c2.y; uic[10]=a2.z+c2.z; uic[11]=a2.w+c2.w;
  }
  float acc[NH][2];
  #pragma unroll
  for (int h = 0; h < NH; ++h) { acc[h][0] = 0.f; acc[h][1] = 0.f; }
  int beg = row_start[wid], end = row_start[wid + 1];
  for (int j = beg; j < end; ++j) {
    int e = sorted[j];
    int s = (e < e0) ? srcp[e] : (e - e0);
    const float4* usp = (const float4*)(u + (long)s * NH);
    float4 u0 = usp[0], u1 = usp[1], u2 = usp[2];
    float w[NH];
    w[0]=uic[0]-u0.x; w[1]=uic[1]-u0.y; w[2]=uic[2]-u0.z;  w[3]=uic[3]-u0.w;
    w[4]=uic[4]-u1.x; w[5]=uic[5]-u1.y; w[6]=uic[6]-u1.z;  w[7]=uic[7]-u1.w;
    w[8]=uic[8]-u2.x; w[9]=uic[9]-u2.y; w[10]=uic[10]-u2.z; w[11]=uic[11]-u2.w;
    float m = w[0];
    #pragma unroll
    for (int h = 1; h < NH; ++h) m = fmaxf(m, w[h]);
    float ssum = 0.f;
    #pragma unroll
    for (int h = 0; h < NH; ++h) { w[h] = __expf(w[h] - m); ssum += w[h]; }
    float inv = 1.f / ssum;
    float2 xv = *(const float2*)(x + (long)s * DHID + 2 * lane);
    #pragma unroll
    for (int h = 0; h < NH; ++h) {
      float a = w[h] * inv;
      acc[h][0] += a * xv.x;
      acc[h][1] += a * xv.y;
    }
  }
  unsigned* Ap = (unsigned*)(A + (long)wid * KDIM);
  #pragma unroll
  for (int h = 0; h < NH; ++h) {
    unsigned pv = (unsigned)f2bf(acc[h][0]) | ((unsigned)f2bf(acc[h][1]) << 16);
    Ap[h * (DHID / 2) + lane] = pv;
  }
}

// ---------------- weight repack: Wcat[c][h*128+k] = Wlin[h*128+c][k], bf16 ----------------

__global__ void prep_wcat_k(const float* __restrict__ Wlin, unsigned short* __restrict__ Wcat) {
  int t = blockIdx.x * blockDim.x + threadIdx.x;  // 128*1536 total
  int c = t / KDIM, f = t - c * KDIM;
  int h = f >> 7, k = f & (DHID - 1);
  Wcat[t] = f2bf(Wlin[((h << 7) + c) * DHID + k]);
}

// ---------------- GEMM: out[n,c] = (A[n,:] . Wcat[c,:]) / deg[n] + bias[c] ----------------

__global__ __launch_bounds__(256) void gemm_k(
    const unsigned short* __restrict__ A, const unsigned short* __restrict__ B,
    const float* __restrict__ bias, const int* __restrict__ row_start,
    float* __restrict__ out, float* __restrict__ bnsum, float* __restrict__ bnsq,
    int M, int relu, int dobn) {
  int w = threadIdx.x >> 6, lane = threadIdx.x & 63;
  int lr = lane & 15, lq = lane >> 4;
  int m0 = blockIdx.x * 64, n0 = w * 32;
  f32x4 acc[4][2];
  #pragma unroll
  for (int mf = 0; mf < 4; ++mf)
    #pragma unroll
    for (int nf = 0; nf < 2; ++nf) acc[mf][nf] = (f32x4){0.f, 0.f, 0.f, 0.f};
  const short* Ap = (const short*)A;
  const short* Bp = (const short*)B;
  long arow[4], brow[2];
  #pragma unroll
  for (int mf = 0; mf < 4; ++mf) arow[mf] = (long)(m0 + mf * 16 + lr) * KDIM + lq * 8;
  #pragma unroll
  for (int nf = 0; nf < 2; ++nf) brow[nf] = (long)(n0 + nf * 16 + lr) * KDIM + lq * 8;
  #pragma unroll 2
  for (int kk = 0; kk < KDIM; kk += 32) {
    short8 av[4], bv[2];
    #pragma unroll
    for (int mf = 0; mf < 4; ++mf) av[mf] = *(const short8*)(Ap + arow[mf] + kk);
    #pragma unroll
    for (int nf = 0; nf < 2; ++nf) bv[nf] = *(const short8*)(Bp + brow[nf] + kk);
    #pragma unroll
    for (int mf = 0; mf < 4; ++mf)
      #pragma unroll
      for (int nf = 0; nf < 2; ++nf)
        acc[mf][nf] = __builtin_amdgcn_mfma_f32_16x16x32_bf16(av[mf], bv[nf], acc[mf][nf], 0, 0, 0);
  }
  // epilogue: /deg + bias, optional relu, optional BN stats
  #pragma unroll
  for (int nf = 0; nf < 2; ++nf) {
    int c = n0 + nf * 16 + lr;
    float bc = bias[c];
    float s_part = 0.f, q_part = 0.f;
    #pragma unroll
    for (int mf = 0; mf < 4; ++mf) {
      int rowb = m0 + mf * 16 + lq * 4;
      #pragma unroll
      for (int r = 0; r < 4; ++r) {
        int row = rowb + r;
        if (row < M) {
          int deg = row_start[row + 1] - row_start[row];
          float v = acc[mf][nf][r] / (float)deg + bc;
          if (relu) v = fmaxf(v, 0.f);
          out[(long)row * DHID + c] = v;
          s_part += v; q_part += v * v;
        }
      }
    }
    if (dobn) {
      s_part += __shfl_xor(s_part, 16); s_part += __shfl_xor(s_part, 32);
      q_part += __shfl_xor(q_part, 16); q_part += __shfl_xor(q_part, 32);
      if (lq == 0) {
        atomicAdd(&bnsum[c], s_part);
        atomicAdd(&bnsq[c], q_part);
      }
    }
  }
}

// ---------------- BatchNorm finalize + apply ----------------

__global__ void bnfin_k(const float* __restrict__ bnsum, const float* __restrict__ bnsq,
                        const float* __restrict__ g, const float* __restrict__ b,
                        float* __restrict__ sc, float* __restrict__ sh, float invn) {
  int c = threadIdx.x;
  float m = bnsum[c] * invn;
  float v = bnsq[c] * invn - m * m;
  float rs = rsqrtf(v + 1e-5f);
  float s = g[c] * rs;
  sc[c] = s;
  sh[c] = b[c] - m * s;
}

__global__ void bnapply_k(const float* __restrict__ in, const float* __restrict__ sc,
                          const float* __restrict__ sh, float* __restrict__ outp, int nvec) {
  int i = blockIdx.x * blockDim.x + threadIdx.x;
  if (i >= nvec) return;
  long idx = (long)i * 4;
  int c = (int)(idx & (DHID - 1));
  float4 v = *(const float4*)(in + idx);
  v.x = v.x * sc[c]     + sh[c];
  v.y = v.y * sc[c + 1] + sh[c + 1];
  v.z = v.z * sc[c + 2] + sh[c + 2];
  v.w = v.w * sc[c + 3] + sh[c + 3];
  *(float4*)(outp + idx) = v;
}

// ---------------- launch ----------------

extern "C" void kernel_launch(void* const* d_in, const int* in_sizes, int n_in,
                              void* d_out, int out_size, void* d_ws, size_t ws_size,
                              hipStream_t stream) {
  const float* x = (const float*)d_in[0];
  const int* ei = (const int*)d_in[1];
  const int N = in_sizes[0] / DHID;
  const int E0 = in_sizes[1] / 2;
  const int ET = E0 + N;
  const int* srcp = ei;
  const int* dstp = ei + E0;
  const float* Wlin[3] = {(const float*)d_in[2], (const float*)d_in[6], (const float*)d_in[10]};
  const float* Wu[3]   = {(const float*)d_in[3], (const float*)d_in[7], (const float*)d_in[11]};
  const float* cc[3]   = {(const float*)d_in[4], (const float*)d_in[8], (const float*)d_in[12]};
  const float* bb[3]   = {(const float*)d_in[5], (const float*)d_in[9], (const float*)d_in[13]};
  const float* bng[2]  = {(const float*)d_in[14], (const float*)d_in[16]};
  const float* bnb[2]  = {(const float*)d_in[15], (const float*)d_in[17]};

  const int MPAD = ((N + 63) / 64) * 64;

  // carve workspace
  size_t o = 0;
  char* base = (char*)d_ws;
  auto carve = [&](size_t bytes) -> char* {
    char* p = base + o;
    o += (bytes + 255) & ~(size_t)255;
    return p;
  };
  int* row_start = (int*)carve((size_t)(N + 1) * 4);
  int* cnt       = (int*)carve((size_t)N * 4);
  int* cursor    = (int*)carve((size_t)N * 4);
  int* sorted    = (int*)carve((size_t)ET * 4);
  float* u       = (float*)carve((size_t)N * NH * 4);
  float* bnbuf   = (float*)carve(4 * DHID * 4);
  float* bnsum = bnbuf, *bnsq = bnbuf + DHID, *bnsc = bnbuf + 2 * DHID, *bnsh = bnbuf + 3 * DHID;
  unsigned short* Wcat = (unsigned short*)carve((size_t)DHID * KDIM * 2);
  float* hA = (float*)carve((size_t)N * DHID * 4);
  float* hB = (float*)carve((size_t)N * DHID * 4);
  unsigned short* A = (unsigned short*)carve((size_t)MPAD * KDIM * 2);
  (void)ws_size; (void)n_in; (void)out_size;

  const int EB = (ET + 255) / 256;
  const int NW = (N + 3) / 4;       // 4 waves (nodes) per 256-thread block
  const int MB = (N + 63) / 64;
  const int AV = (N * DHID / 4 + 255) / 256;

  // sort edges by dst (once; dst list is layer-invariant)
  hipMemsetAsync(cnt, 0, (size_t)N * 4, stream);
  hist_k<<<EB, 256, 0, stream>>>(dstp, cnt, E0, ET);
  scan_k<<<1, 1024, 0, stream>>>(cnt, row_start, cursor, N, ET);
  scatter_k<<<EB, 256, 0, stream>>>(dstp, cursor, sorted, E0, ET);

  const float* hin = x;
  for (int li = 0; li < 3; ++li) {
    const bool last = (li == 2);
    u_k<<<NW, 256, 0, stream>>>(hin, Wu[li], u, N);
    edge_k<<<NW, 256, 0, stream>>>(hin, u, cc[li], srcp, row_start, sorted, A, N, E0);
    prep_wcat_k<<<(DHID * KDIM) / 256, 256, 0, stream>>>(Wlin[li], Wcat);
    if (!last) hipMemsetAsync(bnbuf, 0, 2 * DHID * 4, stream);
    float* outp = last ? (float*)d_out : hA;
    gemm_k<<<MB, 256, 0, stream>>>(A, Wcat, bb[li], row_start, outp, bnsum, bnsq,
                                   N, last ? 0 : 1, last ? 0 : 1);
    if (!last) {
      bnfin_k<<<1, DHID, 0, stream>>>(bnsum, bnsq, bng[li], bnb[li], bnsc, bnsh, 1.f / (float)N);
      bnapply_k<<<AV, 256, 0, stream>>>(hA, bnsc, bnsh, hB, N * DHID / 4);
      hin = hB;
    }
  }
}

// Round 2
// 581.657 us; speedup vs baseline: 1.3312x; 1.3312x over previous
//
#include <hip/hip_runtime.h>
#include <hip/hip_bf16.h>

#define DHID 128
#define NH 12
#define KDIM 1536   // NH * DHID

typedef __attribute__((ext_vector_type(8))) short short8;
typedef __attribute__((ext_vector_type(4))) float f32x4;

static __device__ __forceinline__ unsigned short f2bf(float f) {
  __hip_bfloat16 h = __float2bfloat16(f);
  return __builtin_bit_cast(unsigned short, h);
}

// ---------------- sort (counting sort of edges by dst) ----------------

__global__ void hist_k(const int* __restrict__ dstp, int* __restrict__ cnt, int e0, int et) {
  int e = blockIdx.x * blockDim.x + threadIdx.x;
  if (e >= et) return;
  int d = (e < e0) ? dstp[e] : (e - e0);   // self-loop edges appended at the end
  atomicAdd(&cnt[d], 1);
}

// cnt and cursor may alias (in-place): each element is read before rewrite.
__global__ void scan_k(const int* __restrict__ cnt, int* __restrict__ row_start,
                       int* __restrict__ cursor, int n, int total) {
  __shared__ int part[1024];
  int t = threadIdx.x;
  const int CH = (n + 1023) >> 10;
  int base = t * CH;
  int s = 0;
  for (int j = 0; j < CH; ++j) { int i = base + j; if (i < n) s += cnt[i]; }
  part[t] = s;
  __syncthreads();
  for (int off = 1; off < 1024; off <<= 1) {
    int v = (t >= off) ? part[t - off] : 0;
    __syncthreads();
    part[t] += v;
    __syncthreads();
  }
  int run = (t == 0) ? 0 : part[t - 1];
  for (int j = 0; j < CH; ++j) {
    int i = base + j;
    if (i < n) {
      int c = cnt[i];              // read BEFORE cursor write (may alias)
      row_start[i] = run;
      cursor[i] = run;
      run += c;
    }
  }
  if (t == 0) row_start[n] = total;
}

__global__ void scatter_k(const int* __restrict__ srcp, const int* __restrict__ dstp,
                          int* __restrict__ cursor, int* __restrict__ srcs,
                          int* __restrict__ dsts, int e0, int et) {
  int e = blockIdx.x * blockDim.x + threadIdx.x;
  if (e >= et) return;
  int s = (e < e0) ? srcp[e] : (e - e0);
  int d = (e < e0) ? dstp[e] : (e - e0);
  int pos = atomicAdd(&cursor[d], 1);
  srcs[pos] = s;
  dsts[pos] = d;
}

// ---------------- per-node u = x . Wu[h] ----------------

__global__ void u_k(const float* __restrict__ x, const float* __restrict__ Wu,
                    float* __restrict__ u, int n) {
  int wid = (blockIdx.x * blockDim.x + threadIdx.x) >> 6;
  if (wid >= n) return;
  int lane = threadIdx.x & 63;
  float2 xv = *(const float2*)(x + (long)wid * DHID + 2 * lane);
  #pragma unroll
  for (int h = 0; h < NH; ++h) {
    float2 wv = *(const float2*)(Wu + h * DHID + 2 * lane);
    float p = xv.x * wv.x + xv.y * wv.y;
    p += __shfl_xor(p, 1);  p += __shfl_xor(p, 2);  p += __shfl_xor(p, 4);
    p += __shfl_xor(p, 8);  p += __shfl_xor(p, 16); p += __shfl_xor(p, 32);
    if (lane == 0) u[wid * NH + h] = p;
  }
}

// ---------------- per-edge attention (thread per edge, dst-sorted order) ----------------
// attS[j][h] = softmax_h(u[dst]-u[src]+c) / deg(dst)

__global__ void att_k(const float* __restrict__ u, const float* __restrict__ cvec,
                      const int* __restrict__ srcs, const int* __restrict__ dsts,
                      const int* __restrict__ row_start, float* __restrict__ attS, int et) {
  int j = blockIdx.x * blockDim.x + threadIdx.x;
  if (j >= et) return;
  int s = srcs[j], d = dsts[j];
  const float4* ud = (const float4*)(u + (long)d * NH);
  const float4* us = (const float4*)(u + (long)s * NH);
  const float4* cp = (const float4*)cvec;
  float w[NH];
  #pragma unroll
  for (int q = 0; q < 3; ++q) {
    float4 a = ud[q], b = us[q], c = cp[q];
    w[4*q+0] = a.x - b.x + c.x;
    w[4*q+1] = a.y - b.y + c.y;
    w[4*q+2] = a.z - b.z + c.z;
    w[4*q+3] = a.w - b.w + c.w;
  }
  float m = w[0];
  #pragma unroll
  for (int h = 1; h < NH; ++h) m = fmaxf(m, w[h]);
  float ssum = 0.f;
  #pragma unroll
  for (int h = 0; h < NH; ++h) { w[h] = __expf(w[h] - m); ssum += w[h]; }
  float deg = (float)(row_start[d + 1] - row_start[d]);
  float inv = 1.f / (ssum * deg);
  float4* op = (float4*)(attS + (long)j * NH);
  #pragma unroll
  for (int q = 0; q < 3; ++q) {
    float4 v;
    v.x = w[4*q+0] * inv; v.y = w[4*q+1] * inv;
    v.z = w[4*q+2] * inv; v.w = w[4*q+3] * inv;
    op[q] = v;
  }
}

// ---------------- edge aggregation: A[n,h,:] = sum_j attS[j,h] * x[srcs[j]] ----------------

__global__ void edge_k(const float* __restrict__ x, const float* __restrict__ attS,
                       const int* __restrict__ srcs, const int* __restrict__ row_start,
                       unsigned short* __restrict__ A, int n) {
  int wid = __builtin_amdgcn_readfirstlane((int)((blockIdx.x * blockDim.x + threadIdx.x) >> 6));
  if (wid >= n) return;
  int lane = threadIdx.x & 63;
  float acc[NH][2];
  #pragma unroll
  for (int h = 0; h < NH; ++h) { acc[h][0] = 0.f; acc[h][1] = 0.f; }
  int beg = row_start[wid], end = row_start[wid + 1];
  int j = beg;
  for (; j + 1 < end; j += 2) {
    int s0 = srcs[j], s1 = srcs[j + 1];
    float2 xv0 = *(const float2*)(x + (long)s0 * DHID + 2 * lane);
    float2 xv1 = *(const float2*)(x + (long)s1 * DHID + 2 * lane);
    const float4* a0p = (const float4*)(attS + (long)j * NH);
    float4 a00 = a0p[0], a01 = a0p[1], a02 = a0p[2];
    float4 a10 = a0p[3], a11 = a0p[4], a12 = a0p[5];
    float av0[NH], av1[NH];
    av0[0]=a00.x; av0[1]=a00.y; av0[2]=a00.z;  av0[3]=a00.w;
    av0[4]=a01.x; av0[5]=a01.y; av0[6]=a01.z;  av0[7]=a01.w;
    av0[8]=a02.x; av0[9]=a02.y; av0[10]=a02.z; av0[11]=a02.w;
    av1[0]=a10.x; av1[1]=a10.y; av1[2]=a10.z;  av1[3]=a10.w;
    av1[4]=a11.x; av1[5]=a11.y; av1[6]=a11.z;  av1[7]=a11.w;
    av1[8]=a12.x; av1[9]=a12.y; av1[10]=a12.z; av1[11]=a12.w;
    #pragma unroll
    for (int h = 0; h < NH; ++h) {
      acc[h][0] += av0[h] * xv0.x + av1[h] * xv1.x;
      acc[h][1] += av0[h] * xv0.y + av1[h] * xv1.y;
    }
  }
  if (j < end) {
    int s0 = srcs[j];
    float2 xv0 = *(const float2*)(x + (long)s0 * DHID + 2 * lane);
    const float4* a0p = (const float4*)(attS + (long)j * NH);
    float4 a00 = a0p[0], a01 = a0p[1], a02 = a0p[2];
    float av0[NH];
    av0[0]=a00.x; av0[1]=a00.y; av0[2]=a00.z;  av0[3]=a00.w;
    av0[4]=a01.x; av0[5]=a01.y; av0[6]=a01.z;  av0[7]=a01.w;
    av0[8]=a02.x; av0[9]=a02.y; av0[10]=a02.z; av0[11]=a02.w;
    #pragma unroll
    for (int h = 0; h < NH; ++h) {
      acc[h][0] += av0[h] * xv0.x;
      acc[h][1] += av0[h] * xv0.y;
    }
  }
  unsigned* Ap = (unsigned*)(A + (long)wid * KDIM);
  #pragma unroll
  for (int h = 0; h < NH; ++h) {
    unsigned pv = (unsigned)f2bf(acc[h][0]) | ((unsigned)f2bf(acc[h][1]) << 16);
    Ap[h * (DHID / 2) + lane] = pv;
  }
}

// ---------------- weight repack: Wcat[c][h*128+k] = Wlin[h*128+c][k], bf16 ----------------

__global__ void prep_wcat_k(const float* __restrict__ Wlin, unsigned short* __restrict__ Wcat) {
  int t = blockIdx.x * blockDim.x + threadIdx.x;  // 128*1536 total
  int c = t / KDIM, f = t - c * KDIM;
  int h = f >> 7, k = f & (DHID - 1);
  Wcat[t] = f2bf(Wlin[((h << 7) + c) * DHID + k]);
}

// ---------------- GEMM: out[n,c] = (A[n,:] . Wcat[c,:]) + bias[c] ----------------

__global__ __launch_bounds__(256) void gemm_k(
    const unsigned short* __restrict__ A, const unsigned short* __restrict__ B,
    const float* __restrict__ bias,
    float* __restrict__ out, float* __restrict__ bnsum, float* __restrict__ bnsq,
    int M, int relu, int dobn) {
  int w = threadIdx.x >> 6, lane = threadIdx.x & 63;
  int lr = lane & 15, lq = lane >> 4;
  int m0 = blockIdx.x * 64, n0 = w * 32;
  f32x4 acc[4][2];
  #pragma unroll
  for (int mf = 0; mf < 4; ++mf)
    #pragma unroll
    for (int nf = 0; nf < 2; ++nf) acc[mf][nf] = (f32x4){0.f, 0.f, 0.f, 0.f};
  const short* Ap = (const short*)A;
  const short* Bp = (const short*)B;
  long arow[4], brow[2];
  #pragma unroll
  for (int mf = 0; mf < 4; ++mf) arow[mf] = (long)(m0 + mf * 16 + lr) * KDIM + lq * 8;
  #pragma unroll
  for (int nf = 0; nf < 2; ++nf) brow[nf] = (long)(n0 + nf * 16 + lr) * KDIM + lq * 8;
  #pragma unroll 2
  for (int kk = 0; kk < KDIM; kk += 32) {
    short8 av[4], bv[2];
    #pragma unroll
    for (int mf = 0; mf < 4; ++mf) av[mf] = *(const short8*)(Ap + arow[mf] + kk);
    #pragma unroll
    for (int nf = 0; nf < 2; ++nf) bv[nf] = *(const short8*)(Bp + brow[nf] + kk);
    #pragma unroll
    for (int mf = 0; mf < 4; ++mf)
      #pragma unroll
      for (int nf = 0; nf < 2; ++nf)
        acc[mf][nf] = __builtin_amdgcn_mfma_f32_16x16x32_bf16(av[mf], bv[nf], acc[mf][nf], 0, 0, 0);
  }
  // epilogue: + bias, optional relu, optional BN stats
  #pragma unroll
  for (int nf = 0; nf < 2; ++nf) {
    int c = n0 + nf * 16 + lr;
    float bc = bias[c];
    float s_part = 0.f, q_part = 0.f;
    #pragma unroll
    for (int mf = 0; mf < 4; ++mf) {
      int rowb = m0 + mf * 16 + lq * 4;
      #pragma unroll
      for (int r = 0; r < 4; ++r) {
        int row = rowb + r;
        if (row < M) {
          float v = acc[mf][nf][r] + bc;
          if (relu) v = fmaxf(v, 0.f);
          out[(long)row * DHID + c] = v;
          s_part += v; q_part += v * v;
        }
      }
    }
    if (dobn) {
      s_part += __shfl_xor(s_part, 16); s_part += __shfl_xor(s_part, 32);
      q_part += __shfl_xor(q_part, 16); q_part += __shfl_xor(q_part, 32);
      if (lq == 0) {
        atomicAdd(&bnsum[c], s_part);
        atomicAdd(&bnsq[c], q_part);
      }
    }
  }
}

// ---------------- BatchNorm finalize + apply (in place) ----------------

__global__ void bnfin_k(const float* __restrict__ bnsum, const float* __restrict__ bnsq,
                        const float* __restrict__ g, const float* __restrict__ b,
                        float* __restrict__ sc, float* __restrict__ sh, float invn) {
  int c = threadIdx.x;
  float m = bnsum[c] * invn;
  float v = bnsq[c] * invn - m * m;
  float rs = rsqrtf(v + 1e-5f);
  float s = g[c] * rs;
  sc[c] = s;
  sh[c] = b[c] - m * s;
}

__global__ void bnapply_k(float* __restrict__ buf, const float* __restrict__ sc,
                          const float* __restrict__ sh, int nvec) {
  int i = blockIdx.x * blockDim.x + threadIdx.x;
  if (i >= nvec) return;
  long idx = (long)i * 4;
  int c = (int)(idx & (DHID - 1));
  float4 v = *(const float4*)(buf + idx);
  v.x = v.x * sc[c]     + sh[c];
  v.y = v.y * sc[c + 1] + sh[c + 1];
  v.z = v.z * sc[c + 2] + sh[c + 2];
  v.w = v.w * sc[c + 3] + sh[c + 3];
  *(float4*)(buf + idx) = v;
}

// ---------------- launch ----------------

extern "C" void kernel_launch(void* const* d_in, const int* in_sizes, int n_in,
                              void* d_out, int out_size, void* d_ws, size_t ws_size,
                              hipStream_t stream) {
  const float* x = (const float*)d_in[0];
  const int* ei = (const int*)d_in[1];
  const int N = in_sizes[0] / DHID;
  const int E0 = in_sizes[1] / 2;
  const int ET = E0 + N;
  const int* srcp = ei;
  const int* dstp = ei + E0;
  const float* Wlin[3] = {(const float*)d_in[2], (const float*)d_in[6], (const float*)d_in[10]};
  const float* Wu[3]   = {(const float*)d_in[3], (const float*)d_in[7], (const float*)d_in[11]};
  const float* cc[3]   = {(const float*)d_in[4], (const float*)d_in[8], (const float*)d_in[12]};
  const float* bb[3]   = {(const float*)d_in[5], (const float*)d_in[9], (const float*)d_in[13]};
  const float* bng[2]  = {(const float*)d_in[14], (const float*)d_in[16]};
  const float* bnb[2]  = {(const float*)d_in[15], (const float*)d_in[17]};

  const int MPAD = ((N + 63) / 64) * 64;

  // carve workspace
  size_t o = 0;
  char* base = (char*)d_ws;
  auto carve = [&](size_t bytes) -> char* {
    char* p = base + o;
    o += (bytes + 255) & ~(size_t)255;
    return p;
  };
  int* row_start = (int*)carve((size_t)(N + 1) * 4);
  int* cursor    = (int*)carve((size_t)N * 4);       // doubles as histogram
  int* srcs      = (int*)carve((size_t)ET * 4);
  int* dsts      = (int*)carve((size_t)ET * 4);
  float* u       = (float*)carve((size_t)N * NH * 4);
  float* bnbuf   = (float*)carve(4 * DHID * 4);
  float* bnsum = bnbuf, *bnsq = bnbuf + DHID, *bnsc = bnbuf + 2 * DHID, *bnsh = bnbuf + 3 * DHID;
  unsigned short* Wcat = (unsigned short*)carve((size_t)DHID * KDIM * 2);
  float* attS    = (float*)carve((size_t)ET * NH * 4);
  float* hA      = (float*)carve((size_t)N * DHID * 4);
  unsigned short* A = (unsigned short*)carve((size_t)MPAD * KDIM * 2);
  (void)ws_size; (void)n_in; (void)out_size;

  const int EB = (ET + 255) / 256;
  const int NW = (N + 3) / 4;       // 4 waves (nodes) per 256-thread block
  const int MB = (N + 63) / 64;
  const int AV = (N * DHID / 4 + 255) / 256;

  // sort edges by dst (once; dst list is layer-invariant)
  hipMemsetAsync(cursor, 0, (size_t)N * 4, stream);
  hist_k<<<EB, 256, 0, stream>>>(dstp, cursor, E0, ET);
  scan_k<<<1, 1024, 0, stream>>>(cursor, row_start, cursor, N, ET);
  scatter_k<<<EB, 256, 0, stream>>>(srcp, dstp, cursor, srcs, dsts, E0, ET);

  const float* hin = x;
  for (int li = 0; li < 3; ++li) {
    const bool last = (li == 2);
    u_k<<<NW, 256, 0, stream>>>(hin, Wu[li], u, N);
    att_k<<<EB, 256, 0, stream>>>(u, cc[li], srcs, dsts, row_start, attS, ET);
    edge_k<<<NW, 256, 0, stream>>>(hin, attS, srcs, row_start, A, N);
    prep_wcat_k<<<(DHID * KDIM) / 256, 256, 0, stream>>>(Wlin[li], Wcat);
    if (!last) hipMemsetAsync(bnbuf, 0, 2 * DHID * 4, stream);
    float* outp = last ? (float*)d_out : hA;
    gemm_k<<<MB, 256, 0, stream>>>(A, Wcat, bb[li], outp, bnsum, bnsq,
                                   N, last ? 0 : 1, last ? 0 : 1);
    if (!last) {
      bnfin_k<<<1, DHID, 0, stream>>>(bnsum, bnsq, bng[li], bnb[li], bnsc, bnsh, 1.f / (float)N);
      bnapply_k<<<AV, 256, 0, stream>>>(hA, bnsc, bnsh, N * DHID / 4);
      hin = hA;
    }
  }
}